// Round 1
// 180.031 us; speedup vs baseline: 1.1200x; 1.1200x over previous
//
#include <hip/hip_runtime.h>

#define D 128
#define CAP 128   // slot capacity per node; Poisson(12) in-degree: P(>=128) astronomically small
#define NR 8      // target ranges == XCD count; range = blockIdx % 8 -> XCD-local scatter
typedef unsigned int uint;
typedef unsigned short ushort;
typedef __attribute__((ext_vector_type(8))) short bf16x8;
typedef __attribute__((ext_vector_type(4))) float f32x4;

// ---- bf16x2 pack/unpack (packed uint: low16 = even dim, high16 = odd dim) ----
__device__ __forceinline__ float2 bf2_to_f2(uint v) {
    union { uint u; float f; } a, b;
    a.u = v << 16;
    b.u = v & 0xffff0000u;
    return make_float2(a.f, b.f);
}
__device__ __forceinline__ uint f2_to_bf2(float x, float y) {
    uint xu = __float_as_uint(x), yu = __float_as_uint(y);
    xu += 0x7fffu + ((xu >> 16) & 1u);   // round-to-nearest-even
    yu += 0x7fffu + ((yu >> 16) & 1u);
    return (xu >> 16) | (yu & 0xffff0000u);
}

// ---- K1: XCD-partitioned adjacency build + W cast ----
// Each (chunk, range) block filters its 256-edge chunk to targets in range.
// range = blockIdx % 8 -> all writers of a 3.2 MB slots range live on ONE XCD's L2:
// scattered 4B stores coalesce in-cache and write back once (kills the 48 MB
// bounced-writeback amplification seen in rocprof).
__global__ __launch_bounds__(256) void edge_build_kernel(
        const int* __restrict__ ei, int E, int n,
        int* __restrict__ deg, int* __restrict__ slots,
        const float* __restrict__ W, uint* __restrict__ Wbf, int edgeB) {
    int b = blockIdx.x, t = threadIdx.x;
    if (b < edgeB) {
        int range = b & (NR - 1);
        int e = (b >> 3) * 256 + t;
        if (e < E) {
            int c = ei[E + e];                     // coalesced col read (L3-served for re-reads)
            int per = (n + NR - 1) / NR;           // 6250
            int lo = range * per;
            if (c >= lo && c < lo + per) {
                int r = ei[e];
                int pos = atomicAdd(&deg[c], 1);
                if (pos < CAP) slots[(size_t)c * CAP + pos] = r;
            }
        }
    } else {
        int i = (b - edgeB) * 256 + t;             // W cast: one float2 -> uint per thread
        if (i < (D * D) / 2) {
            float2 wv = ((const float2*)W)[i];
            Wbf[i] = f2_to_bf2(wv.x, wv.y);
        }
    }
}

// ---- K2: u = bf16( dinv[node] * x[node] )  (needs deg complete) ----
// Pre-scaling by D^-1/2 makes BOTH hops unweighted sums: removes the per-neighbor
// random deg[r] gather (a full 64B line each) + rsqrt from hop 1 entirely.
__global__ __launch_bounds__(256) void scale_cast_kernel(
        const float* __restrict__ x, const int* __restrict__ deg,
        uint2* __restrict__ zX, int n) {
    int idx = blockIdx.x * 256 + threadIdx.x;      // one float4 -> uint2 per thread
    if (idx < n * 32) {
        int node = idx >> 5;
        float dv = rsqrtf((float)(deg[node] + 1)); // broadcast load, L1-hit
        float4 v = ((const float4*)x)[idx];
        uint2 o;
        o.x = f2_to_bf2(v.x * dv, v.y * dv);
        o.y = f2_to_bf2(v.z * dv, v.w * dv);
        zX[idx] = o;
    }
}

// ---- K3/K4: unweighted gather-sum hop.
// HOP1: w[c]  = (u[c] + sum u[r]) * dinv^2
// HOP2: z2[c] = (w[c] + sum w[r]) * dinv
// 8/4/2/1 batch tiers: deg~Poisson(12) -> typical node runs 8-batch + 4-batch,
// keeping 12 row loads in flight instead of 8 + 4 serial.
template<bool HOP1>
__global__ __launch_bounds__(256) void prop_kernel(const uint* __restrict__ zin,
                                                   uint* __restrict__ zout,
                                                   const int* __restrict__ deg,
                                                   const int* __restrict__ slots,
                                                   int n) {
    int wv = threadIdx.x >> 6, lane = threadIdx.x & 63;
    int c = blockIdx.x * 4 + wv;
    if (c >= n) return;
    int len = deg[c]; if (len > CAP) len = CAP;
    const int* lst = slots + (size_t)c * CAP;
    size_t selfoff = (size_t)c * 64 + lane;
    float2 acc = bf2_to_f2(zin[selfoff]);          // self-loop term
    int k = 0;
    for (; k + 7 < len; k += 8) {                  // 8 rows in flight
        int r0 = lst[k],     r1 = lst[k + 1], r2 = lst[k + 2], r3 = lst[k + 3];
        int r4 = lst[k + 4], r5 = lst[k + 5], r6 = lst[k + 6], r7 = lst[k + 7];
        uint v0 = zin[(size_t)r0 * 64 + lane], v1 = zin[(size_t)r1 * 64 + lane];
        uint v2 = zin[(size_t)r2 * 64 + lane], v3 = zin[(size_t)r3 * 64 + lane];
        uint v4 = zin[(size_t)r4 * 64 + lane], v5 = zin[(size_t)r5 * 64 + lane];
        uint v6 = zin[(size_t)r6 * 64 + lane], v7 = zin[(size_t)r7 * 64 + lane];
        float2 f0 = bf2_to_f2(v0), f1 = bf2_to_f2(v1), f2 = bf2_to_f2(v2), f3 = bf2_to_f2(v3);
        float2 f4 = bf2_to_f2(v4), f5 = bf2_to_f2(v5), f6 = bf2_to_f2(v6), f7 = bf2_to_f2(v7);
        acc.x += ((f0.x + f1.x) + (f2.x + f3.x)) + ((f4.x + f5.x) + (f6.x + f7.x));
        acc.y += ((f0.y + f1.y) + (f2.y + f3.y)) + ((f4.y + f5.y) + (f6.y + f7.y));
    }
    if (k + 3 < len) {                             // 4-batch tier
        int r0 = lst[k], r1 = lst[k + 1], r2 = lst[k + 2], r3 = lst[k + 3];
        uint v0 = zin[(size_t)r0 * 64 + lane], v1 = zin[(size_t)r1 * 64 + lane];
        uint v2 = zin[(size_t)r2 * 64 + lane], v3 = zin[(size_t)r3 * 64 + lane];
        float2 f0 = bf2_to_f2(v0), f1 = bf2_to_f2(v1), f2 = bf2_to_f2(v2), f3 = bf2_to_f2(v3);
        acc.x += (f0.x + f1.x) + (f2.x + f3.x);
        acc.y += (f0.y + f1.y) + (f2.y + f3.y);
        k += 4;
    }
    if (k + 1 < len) {                             // 2-batch tier
        int r0 = lst[k], r1 = lst[k + 1];
        uint v0 = zin[(size_t)r0 * 64 + lane], v1 = zin[(size_t)r1 * 64 + lane];
        float2 f0 = bf2_to_f2(v0), f1 = bf2_to_f2(v1);
        acc.x += f0.x + f1.x;
        acc.y += f0.y + f1.y;
        k += 2;
    }
    if (k < len) {
        float2 f = bf2_to_f2(zin[(size_t)lst[k] * 64 + lane]);
        acc.x += f.x; acc.y += f.y;
    }
    float s = rsqrtf((float)(len + 1));
    float sc = HOP1 ? s * s : s;
    zout[selfoff] = f2_to_bf2(acc.x * sc, acc.y * sc);
}

// ---- K5: out = relu(z2 @ W^T + b) via MFMA bf16; 64 nodes/block ----
#define GN 64
__global__ __launch_bounds__(256) void gemm_mfma(const uint4* __restrict__ x2,
                                                 const uint4* __restrict__ Wbf,
                                                 const float* __restrict__ bias,
                                                 float* __restrict__ out, int n) {
    __shared__ __align__(16) ushort xs[GN][136];   // +8 pad: conflict-free b128 frag reads
    __shared__ __align__(16) ushort ws[D][136];
    int t = threadIdx.x;
    int n0 = blockIdx.x * GN;
    for (int i = t; i < D * 16; i += 256) {
        int row = i >> 4, c8 = i & 15;
        uint4 v = Wbf[i];
        *(uint4*)&ws[row][c8 * 8] = v;
    }
    for (int i = t; i < GN * 16; i += 256) {
        int row = i >> 4, c8 = i & 15;
        int node = n0 + row;
        uint4 v = (node < n) ? x2[(size_t)node * 16 + c8] : make_uint4(0u, 0u, 0u, 0u);
        *(uint4*)&xs[row][c8 * 8] = v;
    }
    __syncthreads();

    int w = t >> 6, lane = t & 63;
    int m0 = w * 16;
    int mrow = lane & 15, quad = lane >> 4;

    bf16x8 a[4];
#pragma unroll
    for (int q = 0; q < 4; ++q)
        a[q] = *(const bf16x8*)&xs[m0 + mrow][q * 32 + quad * 8];   // A[m=lane&15][k]

    f32x4 acc[8];
#pragma unroll
    for (int ht = 0; ht < 8; ++ht) {
        acc[ht] = (f32x4){0.f, 0.f, 0.f, 0.f};
#pragma unroll
        for (int q = 0; q < 4; ++q) {
            bf16x8 bfr = *(const bf16x8*)&ws[ht * 16 + mrow][q * 32 + quad * 8];  // B[k][n]=W[h=n][d=k]
            acc[ht] = __builtin_amdgcn_mfma_f32_16x16x32_bf16(a[q], bfr, acc[ht], 0, 0, 0);
        }
    }

#pragma unroll
    for (int ht = 0; ht < 8; ++ht) {
        int h = ht * 16 + mrow;
        float bv = bias[h];
#pragma unroll
        for (int reg = 0; reg < 4; ++reg) {
            int node = n0 + m0 + quad * 4 + reg;   // C/D: col=lane&15, row=quad*4+reg
            if (node < n)
                out[(size_t)node * D + h] = fmaxf(acc[ht][reg] + bv, 0.f);
        }
    }
}

extern "C" void kernel_launch(void* const* d_in, const int* in_sizes, int n_in,
                              void* d_out, int out_size, void* d_ws, size_t ws_size,
                              hipStream_t stream) {
    const float* x  = (const float*)d_in[0];
    const int*   ei = (const int*)d_in[1];
    const float* W  = (const float*)d_in[2];
    const float* bias = (const float*)d_in[3];
    float* out = (float*)d_out;
    int N = in_sizes[0] / D;   // 50000
    int E = in_sizes[1] / 2;   // 600000

    char* p = (char*)d_ws;
    auto alloc = [&](size_t bytes) -> void* {
        void* r = p; p += (bytes + 511) & ~(size_t)511; return r;
    };
    int*    deg     = (int*)alloc((size_t)N * 4);
    int*    slots   = (int*)alloc((size_t)N * CAP * 4);   // 25.6 MB adjacency
    uint*   zX      = (uint*)alloc((size_t)N * 64 * 4);   // u  = bf16(dinv*x)
    uint*   zB      = (uint*)alloc((size_t)N * 64 * 4);   // w  = dinv^2*(u+sum u)
    uint*   zA      = (uint*)alloc((size_t)N * 64 * 4);   // z2 = dinv*(w+sum w)
    uint*   Wbf     = (uint*)alloc((size_t)(D * D / 2) * 4);

    int edgeB = ((E + 255) / 256) * NR;    // 2344 chunks x 8 ranges = 18752 (mult of 8: keeps %8->XCD map)
    int wB    = ((D * D / 2) + 255) / 256; // 32
    int xB    = (N * 32 + 255) / 256;      // 6250

    hipMemsetAsync(deg, 0, (size_t)N * 4, stream);
    edge_build_kernel<<<edgeB + wB, 256, 0, stream>>>(ei, E, N, deg, slots, W, Wbf, edgeB);
    scale_cast_kernel<<<xB, 256, 0, stream>>>(x, deg, (uint2*)zX, N);
    prop_kernel<true ><<<(N + 3) / 4, 256, 0, stream>>>(zX, zB, deg, slots, N);
    prop_kernel<false><<<(N + 3) / 4, 256, 0, stream>>>(zB, zA, deg, slots, N);
    gemm_mfma<<<(N + GN - 1) / GN, 256, 0, stream>>>((const uint4*)zA, (const uint4*)Wbf, bias, out, N);
}